// Round 5
// baseline (79.651 us; speedup 1.0000x reference)
//
#include <hip/hip_runtime.h>

#define B_N 256
#define B_C 256
#define MID 128
#define NELEM (B_N * B_C)
#define DEPTH 8

typedef float f32x4 __attribute__((ext_vector_type(4)));
typedef __bf16 bf16x8 __attribute__((ext_vector_type(8)));
typedef short short8 __attribute__((ext_vector_type(8)));

__device__ __forceinline__ float bf2f(unsigned short h) {
  return __builtin_bit_cast(float, (unsigned int)h << 16);
}

// native casts -> v_cvt_pk_bf16_f32 (RTNE)
__device__ __forceinline__ short8 cvt8(float4 a, float4 b) {
  union { unsigned short us[8]; short8 v; } P;
  P.us[0] = __builtin_bit_cast(unsigned short, (__bf16)a.x);
  P.us[1] = __builtin_bit_cast(unsigned short, (__bf16)a.y);
  P.us[2] = __builtin_bit_cast(unsigned short, (__bf16)a.z);
  P.us[3] = __builtin_bit_cast(unsigned short, (__bf16)a.w);
  P.us[4] = __builtin_bit_cast(unsigned short, (__bf16)b.x);
  P.us[5] = __builtin_bit_cast(unsigned short, (__bf16)b.y);
  P.us[6] = __builtin_bit_cast(unsigned short, (__bf16)b.z);
  P.us[7] = __builtin_bit_cast(unsigned short, (__bf16)b.w);
  return P.v;
}

// swizzled LDS element offset for the 8-element chunk (i, tid)
__device__ __forceinline__ int xs_off(int i, int tid) {
  const int e8 = i * 4096 + tid * 8;
  const int r = e8 >> 8;
  const int q = (e8 >> 3) & 31;
  return (r << 8) + ((q ^ (r & 7)) << 3);
}

// one output row-chunk: read LDS, scale by wexp[row], nt-store to out
__device__ __forceinline__ void out_row(
    const unsigned short* __restrict__ Xs, const float* __restrict__ wexp,
    float* __restrict__ ob, int i, int tid)
{
  const int e8 = i * 4096 + tid * 8;
  union { short8 v; unsigned short us[8]; } P;
  P.v = *reinterpret_cast<const short8*>(&Xs[xs_off(i, tid)]);
  const float wt = wexp[e8 >> 8];
  f32x4 o0, o1;
  o0[0] = bf2f(P.us[0]) * wt; o0[1] = bf2f(P.us[1]) * wt;
  o0[2] = bf2f(P.us[2]) * wt; o0[3] = bf2f(P.us[3]) * wt;
  o1[0] = bf2f(P.us[4]) * wt; o1[1] = bf2f(P.us[5]) * wt;
  o1[2] = bf2f(P.us[6]) * wt; o1[3] = bf2f(P.us[7]) * wt;
  __builtin_nontemporal_store(o0, reinterpret_cast<f32x4*>(ob + e8));
  __builtin_nontemporal_store(o1, reinterpret_cast<f32x4*>(ob + e8 + 4));
}

// Split-pass compute: sim rows in two halves, acc = 64 regs.
//   rp[n]  = sum_m sim[m,n]^2
//   u~[n]  = sum_m sim[m,n] * smid[m] * kern[m],  smid[m] = sim[m,MID]
// smid of each pass's rows held by wave 4, lanes lr==0 (col MID).
// logits: w[n] = u~[n] * rinv[n] * rinv[MID] + bias[n].
__device__ __forceinline__ void compute_batch(
    const unsigned short* __restrict__ Xs, float* smid_s, float* r2s,
    float* wlog, float* wexp, const float* kern_s,
    const float* __restrict__ bias, int tid)
{
  const int w  = tid >> 6;
  const int l  = tid & 63;
  const int lr = l & 15;
  const int g  = l >> 4;
  const int sw = lr & 7;
  const int rb0 = 32 * w + lr;
  const int rb1 = rb0 + 16;

  float rp0 = 0.f, rp1 = 0.f, up0 = 0.f, up1 = 0.f;

  #pragma unroll
  for (int p = 0; p < 2; ++p) {
    f32x4 acc[8][2];
    #pragma unroll
    for (int tt = 0; tt < 8; ++tt) {
      acc[tt][0] = {0.f, 0.f, 0.f, 0.f};
      acc[tt][1] = {0.f, 0.f, 0.f, 0.f};
    }
    #pragma unroll
    for (int kk = 0; kk < 8; ++kk) {
      const int qs = (((4 * kk + g) ^ sw) << 3);
      const bf16x8 bf0 = __builtin_bit_cast(bf16x8,
          *reinterpret_cast<const short8*>(&Xs[(rb0 << 8) + qs]));
      const bf16x8 bf1 = __builtin_bit_cast(bf16x8,
          *reinterpret_cast<const short8*>(&Xs[(rb1 << 8) + qs]));
      #pragma unroll
      for (int tt = 0; tt < 8; ++tt) {
        const int row = 16 * (8 * p + tt) + lr;
        const bf16x8 af = __builtin_bit_cast(bf16x8,
            *reinterpret_cast<const short8*>(&Xs[(row << 8) + qs]));
        acc[tt][0] = __builtin_amdgcn_mfma_f32_16x16x32_bf16(af, bf0, acc[tt][0], 0, 0, 0);
        acc[tt][1] = __builtin_amdgcn_mfma_f32_16x16x32_bf16(af, bf1, acc[tt][1], 0, 0, 0);
      }
    }
    #pragma unroll
    for (int tt = 0; tt < 8; ++tt) {
      #pragma unroll
      for (int r = 0; r < 4; ++r) {
        rp0 += acc[tt][0][r] * acc[tt][0][r];
        rp1 += acc[tt][1][r] * acc[tt][1][r];
      }
    }
    if (w == 4 && lr == 0) {
      #pragma unroll
      for (int tt = 0; tt < 8; ++tt) {
        #pragma unroll
        for (int r = 0; r < 4; ++r)
          smid_s[128 * p + 16 * tt + 4 * g + r] = acc[tt][0][r];
      }
    }
    __syncthreads();
    #pragma unroll
    for (int tt = 0; tt < 8; ++tt) {
      #pragma unroll
      for (int r = 0; r < 4; ++r) {
        const int m = 128 * p + 16 * tt + 4 * g + r;
        const float y = smid_s[m] * kern_s[m];
        up0 += acc[tt][0][r] * y;
        up1 += acc[tt][1][r] * y;
      }
    }
  }

  rp0 += __shfl_xor(rp0, 16); rp0 += __shfl_xor(rp0, 32);
  rp1 += __shfl_xor(rp1, 16); rp1 += __shfl_xor(rp1, 32);
  up0 += __shfl_xor(up0, 16); up0 += __shfl_xor(up0, 32);
  up1 += __shfl_xor(up1, 16); up1 += __shfl_xor(up1, 32);
  if (l < 16) {
    r2s[32 * w + l]       = rp0;
    r2s[32 * w + 16 + l]  = rp1;
    wlog[32 * w + l]      = up0;
    wlog[32 * w + 16 + l] = up1;
  }
  __syncthreads();

  if (tid < B_N) {
    const float rinvm = rsqrtf(fmaxf(r2s[MID], 1e-12f));
    wlog[tid] = wlog[tid] * rsqrtf(fmaxf(r2s[tid], 1e-12f)) * rinvm + bias[tid];
  }
  __syncthreads();

  if (tid < 64) {
    const float a0 = wlog[tid], a1 = wlog[tid + 64], a2 = wlog[tid + 128], a3 = wlog[tid + 192];
    float mx = fmaxf(fmaxf(a0, a1), fmaxf(a2, a3));
    #pragma unroll
    for (int off = 32; off >= 1; off >>= 1) mx = fmaxf(mx, __shfl_xor(mx, off));
    const float e0 = __expf(a0 - mx), e1 = __expf(a1 - mx), e2 = __expf(a2 - mx), e3 = __expf(a3 - mx);
    float s = e0 + e1 + e2 + e3;
    #pragma unroll
    for (int off = 32; off >= 1; off >>= 1) s += __shfl_xor(s, off);
    const float inv = 1.0f / s;
    wexp[tid] = e0 * inv; wexp[tid + 64] = e1 * inv;
    wexp[tid + 128] = e2 * inv; wexp[tid + 192] = e3 * inv;
  }
  __syncthreads();
}

// Persistent: 256 blocks x 2 batches. Merged phase overlaps W(b0) with R(b1).
// launch_bounds(512,1): LDS (133KB) already limits to 1 block/CU; the looser
// bound raises the compiler VGPR cap (128 -> 256) so pf stays in registers.
__global__ __launch_bounds__(512, 1) void spat_attn(
    const float* __restrict__ x, const float* __restrict__ kern,
    const float* __restrict__ bias, float* __restrict__ out, int nb)
{
  __shared__ __align__(16) unsigned short Xs[NELEM];  // 128 KB swizzled bf16
  __shared__ float smid_s[B_N];
  __shared__ float r2s[B_N];
  __shared__ float wlog[B_N];
  __shared__ float wexp[B_N];
  __shared__ float kern_s[B_N];

  const int tid = threadIdx.x;
  const int b0 = blockIdx.x;
  const int b1 = blockIdx.x + gridDim.x;

  if (tid < B_N) kern_s[tid] = kern[tid];

  // ---- R0: load b0 -> cvt -> swizzled LDS ----
  {
    const float* __restrict__ xb = x + (size_t)b0 * NELEM;
    #pragma unroll 4
    for (int i = 0; i < 16; ++i) {
      const float4 f0 = *reinterpret_cast<const float4*>(xb + i * 4096 + tid * 8);
      const float4 f1 = *reinterpret_cast<const float4*>(xb + i * 4096 + tid * 8 + 4);
      *reinterpret_cast<short8*>(&Xs[xs_off(i, tid)]) = cvt8(f0, f1);
    }
  }
  __syncthreads();

  // ---- C0 ----
  compute_batch(Xs, smid_s, r2s, wlog, wexp, kern_s, bias, tid);

  // ---- Merged: W(b0) || R(b1), per-wave row ownership, depth-8 pipeline ----
  float* __restrict__ ob0 = out + (size_t)b0 * NELEM;
  if (b1 < nb) {
    const float* __restrict__ xb1 = x + (size_t)b1 * NELEM;
    float4 pf[2 * DEPTH];
    #pragma unroll
    for (int j = 0; j < DEPTH; ++j) {
      pf[2 * j]     = *reinterpret_cast<const float4*>(xb1 + j * 4096 + tid * 8);
      pf[2 * j + 1] = *reinterpret_cast<const float4*>(xb1 + j * 4096 + tid * 8 + 4);
    }
    #pragma unroll
    for (int i = 0; i < 16; ++i) {
      out_row(Xs, wexp, ob0, i, tid);             // read own LDS rows (b0)
      const int s = i & (DEPTH - 1);
      *reinterpret_cast<short8*>(&Xs[xs_off(i, tid)]) = cvt8(pf[2 * s], pf[2 * s + 1]);
      if (i + DEPTH < 16) {
        pf[2 * s]     = *reinterpret_cast<const float4*>(xb1 + (i + DEPTH) * 4096 + tid * 8);
        pf[2 * s + 1] = *reinterpret_cast<const float4*>(xb1 + (i + DEPTH) * 4096 + tid * 8 + 4);
      }
    }
    __syncthreads();   // all rows of b1 in LDS

    // ---- C1 + W1 ----
    compute_batch(Xs, smid_s, r2s, wlog, wexp, kern_s, bias, tid);
    float* __restrict__ ob1 = out + (size_t)b1 * NELEM;
    #pragma unroll 4
    for (int i = 0; i < 16; ++i) out_row(Xs, wexp, ob1, i, tid);
  } else {
    #pragma unroll 4
    for (int i = 0; i < 16; ++i) out_row(Xs, wexp, ob0, i, tid);
  }
}

extern "C" void kernel_launch(void* const* d_in, const int* in_sizes, int n_in,
                              void* d_out, int out_size, void* d_ws, size_t ws_size,
                              hipStream_t stream) {
  const float* x    = (const float*)d_in[0];
  const float* kern = (const float*)d_in[1];
  const float* bias = (const float*)d_in[2];
  float* out = (float*)d_out;
  const int nb = in_sizes[0] / NELEM;          // 512 batches
  const int grid = (nb + 1) / 2;               // 256 persistent blocks
  spat_attn<<<dim3(grid), dim3(512), 0, stream>>>(x, kern, bias, out, nb);
}

// Round 6
// 76.828 us; speedup vs baseline: 1.0367x; 1.0367x over previous
//
#include <hip/hip_runtime.h>

#define B_N 256
#define B_C 256
#define MID 128
#define NELEM (B_N * B_C)
#define DEPTH 8

typedef float f32x4 __attribute__((ext_vector_type(4)));
typedef __bf16 bf16x8 __attribute__((ext_vector_type(8)));
typedef short short8 __attribute__((ext_vector_type(8)));

__device__ __forceinline__ float bf2f(unsigned short h) {
  return __builtin_bit_cast(float, (unsigned int)h << 16);
}

// native casts -> v_cvt_pk_bf16_f32 (RTNE)
__device__ __forceinline__ short8 cvt8(float4 a, float4 b) {
  union { unsigned short us[8]; short8 v; } P;
  P.us[0] = __builtin_bit_cast(unsigned short, (__bf16)a.x);
  P.us[1] = __builtin_bit_cast(unsigned short, (__bf16)a.y);
  P.us[2] = __builtin_bit_cast(unsigned short, (__bf16)a.z);
  P.us[3] = __builtin_bit_cast(unsigned short, (__bf16)a.w);
  P.us[4] = __builtin_bit_cast(unsigned short, (__bf16)b.x);
  P.us[5] = __builtin_bit_cast(unsigned short, (__bf16)b.y);
  P.us[6] = __builtin_bit_cast(unsigned short, (__bf16)b.z);
  P.us[7] = __builtin_bit_cast(unsigned short, (__bf16)b.w);
  return P.v;
}

// swizzled LDS element offset for the 8-element chunk (i, tid)
__device__ __forceinline__ int xs_off(int i, int tid) {
  const int e8 = i * 4096 + tid * 8;
  const int r = e8 >> 8;
  const int q = (e8 >> 3) & 31;
  return (r << 8) + ((q ^ (r & 7)) << 3);
}

// one output row-chunk: read LDS, scale by wexp[row], plain f32 store
// (NOT nontemporal: two 16B stores per lane at 32B stride are half-line
//  each; L2 must merge them, nt blocks the merge -> 1.5x HBM writes)
__device__ __forceinline__ void out_row(
    const unsigned short* __restrict__ Xs, const float* __restrict__ wexp,
    float* __restrict__ ob, int i, int tid)
{
  const int e8 = i * 4096 + tid * 8;
  union { short8 v; unsigned short us[8]; } P;
  P.v = *reinterpret_cast<const short8*>(&Xs[xs_off(i, tid)]);
  const float wt = wexp[e8 >> 8];
  f32x4 o0, o1;
  o0[0] = bf2f(P.us[0]) * wt; o0[1] = bf2f(P.us[1]) * wt;
  o0[2] = bf2f(P.us[2]) * wt; o0[3] = bf2f(P.us[3]) * wt;
  o1[0] = bf2f(P.us[4]) * wt; o1[1] = bf2f(P.us[5]) * wt;
  o1[2] = bf2f(P.us[6]) * wt; o1[3] = bf2f(P.us[7]) * wt;
  *reinterpret_cast<f32x4*>(ob + e8)     = o0;
  *reinterpret_cast<f32x4*>(ob + e8 + 4) = o1;
}

// Split-pass compute: sim rows in two halves, acc = 64 regs.
//   rp[n]  = sum_m sim[m,n]^2
//   u~[n]  = sum_m sim[m,n] * smid[m] * kern[m],  smid[m] = sim[m,MID]
// smid of each pass's rows held by wave 4, lanes lr==0 (col MID).
// logits: w[n] = u~[n] * rinv[n] * rinv[MID] + bias[n].
__device__ __forceinline__ void compute_batch(
    const unsigned short* __restrict__ Xs, float* smid_s, float* r2s,
    float* wlog, float* wexp, const float* kern_s,
    const float* __restrict__ bias, int tid)
{
  const int w  = tid >> 6;
  const int l  = tid & 63;
  const int lr = l & 15;
  const int g  = l >> 4;
  const int sw = lr & 7;
  const int rb0 = 32 * w + lr;
  const int rb1 = rb0 + 16;

  float rp0 = 0.f, rp1 = 0.f, up0 = 0.f, up1 = 0.f;

  #pragma unroll
  for (int p = 0; p < 2; ++p) {
    f32x4 acc[8][2];
    #pragma unroll
    for (int tt = 0; tt < 8; ++tt) {
      acc[tt][0] = {0.f, 0.f, 0.f, 0.f};
      acc[tt][1] = {0.f, 0.f, 0.f, 0.f};
    }
    #pragma unroll
    for (int kk = 0; kk < 8; ++kk) {
      const int qs = (((4 * kk + g) ^ sw) << 3);
      const bf16x8 bf0 = __builtin_bit_cast(bf16x8,
          *reinterpret_cast<const short8*>(&Xs[(rb0 << 8) + qs]));
      const bf16x8 bf1 = __builtin_bit_cast(bf16x8,
          *reinterpret_cast<const short8*>(&Xs[(rb1 << 8) + qs]));
      #pragma unroll
      for (int tt = 0; tt < 8; ++tt) {
        const int row = 16 * (8 * p + tt) + lr;
        const bf16x8 af = __builtin_bit_cast(bf16x8,
            *reinterpret_cast<const short8*>(&Xs[(row << 8) + qs]));
        acc[tt][0] = __builtin_amdgcn_mfma_f32_16x16x32_bf16(af, bf0, acc[tt][0], 0, 0, 0);
        acc[tt][1] = __builtin_amdgcn_mfma_f32_16x16x32_bf16(af, bf1, acc[tt][1], 0, 0, 0);
      }
    }
    #pragma unroll
    for (int tt = 0; tt < 8; ++tt) {
      #pragma unroll
      for (int r = 0; r < 4; ++r) {
        rp0 += acc[tt][0][r] * acc[tt][0][r];
        rp1 += acc[tt][1][r] * acc[tt][1][r];
      }
    }
    if (w == 4 && lr == 0) {
      #pragma unroll
      for (int tt = 0; tt < 8; ++tt) {
        #pragma unroll
        for (int r = 0; r < 4; ++r)
          smid_s[128 * p + 16 * tt + 4 * g + r] = acc[tt][0][r];
      }
    }
    __syncthreads();
    #pragma unroll
    for (int tt = 0; tt < 8; ++tt) {
      #pragma unroll
      for (int r = 0; r < 4; ++r) {
        const int m = 128 * p + 16 * tt + 4 * g + r;
        const float y = smid_s[m] * kern_s[m];
        up0 += acc[tt][0][r] * y;
        up1 += acc[tt][1][r] * y;
      }
    }
  }

  rp0 += __shfl_xor(rp0, 16); rp0 += __shfl_xor(rp0, 32);
  rp1 += __shfl_xor(rp1, 16); rp1 += __shfl_xor(rp1, 32);
  up0 += __shfl_xor(up0, 16); up0 += __shfl_xor(up0, 32);
  up1 += __shfl_xor(up1, 16); up1 += __shfl_xor(up1, 32);
  if (l < 16) {
    r2s[32 * w + l]       = rp0;
    r2s[32 * w + 16 + l]  = rp1;
    wlog[32 * w + l]      = up0;
    wlog[32 * w + 16 + l] = up1;
  }
  __syncthreads();

  if (tid < B_N) {
    const float rinvm = rsqrtf(fmaxf(r2s[MID], 1e-12f));
    wlog[tid] = wlog[tid] * rsqrtf(fmaxf(r2s[tid], 1e-12f)) * rinvm + bias[tid];
  }
  __syncthreads();

  if (tid < 64) {
    const float a0 = wlog[tid], a1 = wlog[tid + 64], a2 = wlog[tid + 128], a3 = wlog[tid + 192];
    float mx = fmaxf(fmaxf(a0, a1), fmaxf(a2, a3));
    #pragma unroll
    for (int off = 32; off >= 1; off >>= 1) mx = fmaxf(mx, __shfl_xor(mx, off));
    const float e0 = __expf(a0 - mx), e1 = __expf(a1 - mx), e2 = __expf(a2 - mx), e3 = __expf(a3 - mx);
    float s = e0 + e1 + e2 + e3;
    #pragma unroll
    for (int off = 32; off >= 1; off >>= 1) s += __shfl_xor(s, off);
    const float inv = 1.0f / s;
    wexp[tid] = e0 * inv; wexp[tid + 64] = e1 * inv;
    wexp[tid + 128] = e2 * inv; wexp[tid + 192] = e3 * inv;
  }
  __syncthreads();
}

// Persistent: 256 blocks x 2 batches. Merged phase overlaps W(b0) with R(b1):
// wave w only touches rows {16i+2w, 16i+2w+1} in out/fill paths -> disjoint
// across waves -> refill own rows right after reading them, no barrier.
__global__ __launch_bounds__(512, 1) void spat_attn(
    const float* __restrict__ x, const float* __restrict__ kern,
    const float* __restrict__ bias, float* __restrict__ out, int nb)
{
  __shared__ __align__(16) unsigned short Xs[NELEM];  // 128 KB swizzled bf16
  __shared__ float smid_s[B_N];
  __shared__ float r2s[B_N];
  __shared__ float wlog[B_N];
  __shared__ float wexp[B_N];
  __shared__ float kern_s[B_N];

  const int tid = threadIdx.x;
  const int b0 = blockIdx.x;
  const int b1 = blockIdx.x + gridDim.x;

  if (tid < B_N) kern_s[tid] = kern[tid];

  // ---- R0: load b0 -> cvt -> swizzled LDS ----
  {
    const float* __restrict__ xb = x + (size_t)b0 * NELEM;
    #pragma unroll 4
    for (int i = 0; i < 16; ++i) {
      const float4 f0 = *reinterpret_cast<const float4*>(xb + i * 4096 + tid * 8);
      const float4 f1 = *reinterpret_cast<const float4*>(xb + i * 4096 + tid * 8 + 4);
      *reinterpret_cast<short8*>(&Xs[xs_off(i, tid)]) = cvt8(f0, f1);
    }
  }
  __syncthreads();

  // ---- C0 ----
  compute_batch(Xs, smid_s, r2s, wlog, wexp, kern_s, bias, tid);

  // ---- Merged: W(b0) || R(b1), per-wave row ownership, depth-8 pipeline ----
  float* __restrict__ ob0 = out + (size_t)b0 * NELEM;
  if (b1 < nb) {
    const float* __restrict__ xb1 = x + (size_t)b1 * NELEM;
    float4 pf[2 * DEPTH];
    #pragma unroll
    for (int j = 0; j < DEPTH; ++j) {
      pf[2 * j]     = *reinterpret_cast<const float4*>(xb1 + j * 4096 + tid * 8);
      pf[2 * j + 1] = *reinterpret_cast<const float4*>(xb1 + j * 4096 + tid * 8 + 4);
    }
    #pragma unroll
    for (int i = 0; i < 16; ++i) {
      out_row(Xs, wexp, ob0, i, tid);             // read own LDS rows (b0)
      const int s = i & (DEPTH - 1);
      *reinterpret_cast<short8*>(&Xs[xs_off(i, tid)]) = cvt8(pf[2 * s], pf[2 * s + 1]);
      if (i + DEPTH < 16) {
        pf[2 * s]     = *reinterpret_cast<const float4*>(xb1 + (i + DEPTH) * 4096 + tid * 8);
        pf[2 * s + 1] = *reinterpret_cast<const float4*>(xb1 + (i + DEPTH) * 4096 + tid * 8 + 4);
      }
    }
    __syncthreads();   // all rows of b1 in LDS

    // ---- C1 + W1 ----
    compute_batch(Xs, smid_s, r2s, wlog, wexp, kern_s, bias, tid);
    float* __restrict__ ob1 = out + (size_t)b1 * NELEM;
    #pragma unroll 4
    for (int i = 0; i < 16; ++i) out_row(Xs, wexp, ob1, i, tid);
  } else {
    #pragma unroll 4
    for (int i = 0; i < 16; ++i) out_row(Xs, wexp, ob0, i, tid);
  }
}

extern "C" void kernel_launch(void* const* d_in, const int* in_sizes, int n_in,
                              void* d_out, int out_size, void* d_ws, size_t ws_size,
                              hipStream_t stream) {
  const float* x    = (const float*)d_in[0];
  const float* kern = (const float*)d_in[1];
  const float* bias = (const float*)d_in[2];
  float* out = (float*)d_out;
  const int nb = in_sizes[0] / NELEM;          // 512 batches
  const int grid = (nb + 1) / 2;               // 256 persistent blocks
  spat_attn<<<dim3(grid), dim3(512), 0, stream>>>(x, kern, bias, out, nb);
}

// Round 7
// 70.914 us; speedup vs baseline: 1.1232x; 1.0834x over previous
//
#include <hip/hip_runtime.h>

#define B_N 256
#define B_C 256
#define MID 128
#define NELEM (B_N * B_C)

typedef float f32x4 __attribute__((ext_vector_type(4)));
typedef __bf16 bf16x8 __attribute__((ext_vector_type(8)));
typedef short short8 __attribute__((ext_vector_type(8)));

__device__ __forceinline__ float bf2f(unsigned short h) {
  return __builtin_bit_cast(float, (unsigned int)h << 16);
}

// native casts -> v_cvt_pk_bf16_f32 (RTNE)
__device__ __forceinline__ short8 cvt8(float4 a, float4 b) {
  union { unsigned short us[8]; short8 v; } P;
  P.us[0] = __builtin_bit_cast(unsigned short, (__bf16)a.x);
  P.us[1] = __builtin_bit_cast(unsigned short, (__bf16)a.y);
  P.us[2] = __builtin_bit_cast(unsigned short, (__bf16)a.z);
  P.us[3] = __builtin_bit_cast(unsigned short, (__bf16)a.w);
  P.us[4] = __builtin_bit_cast(unsigned short, (__bf16)b.x);
  P.us[5] = __builtin_bit_cast(unsigned short, (__bf16)b.y);
  P.us[6] = __builtin_bit_cast(unsigned short, (__bf16)b.z);
  P.us[7] = __builtin_bit_cast(unsigned short, (__bf16)b.w);
  return P.v;
}

// One block per batch, 512 threads (8 waves). X staged into LDS in 4 K-chunks
// of 64 cols, pipelined with the MFMA loop: loads(c+1) issue before MFMA(c),
// cvt+ds_write(c+1) after, one barrier per chunk. Full X ends LDS-resident
// for the output phase (no re-read of x). Swizzle q^(r&7) is closed within
// each 8-chunk group, so chunk LDS regions are disjoint.
__global__ __launch_bounds__(512, 1) void spat_attn(
    const float* __restrict__ x, const float* __restrict__ kern,
    const float* __restrict__ bias, float* __restrict__ out)
{
  __shared__ __align__(16) unsigned short Xs[NELEM];  // 128 KB swizzled bf16
  __shared__ float smid[B_N];
  __shared__ float r2s[B_N];
  __shared__ float vb[B_N];
  __shared__ float wlog[B_N];
  __shared__ float wexp[B_N];

  const int tid = threadIdx.x;
  const int b = blockIdx.x;
  const float* __restrict__ xb = x + (size_t)b * NELEM;

  // MFMA lane geometry
  const int w  = tid >> 6;
  const int l  = tid & 63;
  const int lr = l & 15;
  const int g  = l >> 4;
  const int sw = lr & 7;
  const int rb0 = 32 * w + lr;
  const int rb1 = rb0 + 16;

  // staging geometry: thread -> (row sr, half sh); 32 floats per chunk step
  const int sr  = tid >> 1;
  const int sh  = tid & 1;
  const int srs = sr & 7;
  const int sq0 = 4 * sh;                       // q offset within chunk
  const float* __restrict__ sbase = xb + sr * B_C + sh * 32;

  f32x4 acc[16][2];
  #pragma unroll
  for (int t = 0; t < 16; ++t) {
    acc[t][0] = {0.f, 0.f, 0.f, 0.f};
    acc[t][1] = {0.f, 0.f, 0.f, 0.f};
  }

  float4 st[8];

  // ---- prologue: stage chunk 0 ----
  #pragma unroll
  for (int j = 0; j < 8; ++j)
    st[j] = *reinterpret_cast<const float4*>(sbase + 4 * j);
  #pragma unroll
  for (int m = 0; m < 4; ++m)
    *reinterpret_cast<short8*>(&Xs[(sr << 8) + (((sq0 + m) ^ srs) << 3)]) =
        cvt8(st[2 * m], st[2 * m + 1]);
  __syncthreads();

  // ---- pipelined chunks: loads(c+1) || MFMA(c), then write(c+1) ----
  #pragma unroll
  for (int c = 0; c < 4; ++c) {
    if (c < 3) {
      #pragma unroll
      for (int j = 0; j < 8; ++j)
        st[j] = *reinterpret_cast<const float4*>(sbase + (c + 1) * 64 + 4 * j);
    }
    #pragma unroll
    for (int kk = 2 * c; kk < 2 * c + 2; ++kk) {
      const int qs = (((4 * kk + g) ^ sw) << 3);
      const bf16x8 bf0 = __builtin_bit_cast(bf16x8,
          *reinterpret_cast<const short8*>(&Xs[(rb0 << 8) + qs]));
      const bf16x8 bf1 = __builtin_bit_cast(bf16x8,
          *reinterpret_cast<const short8*>(&Xs[(rb1 << 8) + qs]));
      #pragma unroll
      for (int t = 0; t < 16; ++t) {
        const bf16x8 af = __builtin_bit_cast(bf16x8,
            *reinterpret_cast<const short8*>(&Xs[((16 * t + lr) << 8) + qs]));
        acc[t][0] = __builtin_amdgcn_mfma_f32_16x16x32_bf16(af, bf0, acc[t][0], 0, 0, 0);
        acc[t][1] = __builtin_amdgcn_mfma_f32_16x16x32_bf16(af, bf1, acc[t][1], 0, 0, 0);
      }
    }
    if (c < 3) {
      #pragma unroll
      for (int m = 0; m < 4; ++m)
        *reinterpret_cast<short8*>(
            &Xs[(sr << 8) + (((8 * (c + 1) + sq0 + m) ^ srs) << 3)]) =
            cvt8(st[2 * m], st[2 * m + 1]);
      __syncthreads();
    }
  }

  // ---- reductions (R1-verified): r2 per column == per row by symmetry ----
  float rp0 = 0.f, rp1 = 0.f;
  #pragma unroll
  for (int t = 0; t < 16; ++t) {
    #pragma unroll
    for (int r = 0; r < 4; ++r) {
      rp0 += acc[t][0][r] * acc[t][0][r];
      rp1 += acc[t][1][r] * acc[t][1][r];
    }
  }
  rp0 += __shfl_xor(rp0, 16); rp0 += __shfl_xor(rp0, 32);
  rp1 += __shfl_xor(rp1, 16); rp1 += __shfl_xor(rp1, 32);
  if (l < 16) {
    r2s[32 * w + l]      = rp0;
    r2s[32 * w + 16 + l] = rp1;
    smid[32 * w + l]      = acc[8][0][0];   // row MID: tile 8, reg 0, g==0
    smid[32 * w + 16 + l] = acc[8][1][0];
  }
  __syncthreads();

  if (tid < B_N) {
    const float rinvm = rsqrtf(fmaxf(r2s[MID], 1e-12f));
    vb[tid] = smid[tid] * rinvm * kern[tid];
  }
  __syncthreads();

  float up0 = 0.f, up1 = 0.f;
  #pragma unroll
  for (int t = 0; t < 16; ++t) {
    #pragma unroll
    for (int r = 0; r < 4; ++r) {
      const float vv = vb[16 * t + 4 * g + r];
      up0 += acc[t][0][r] * vv;
      up1 += acc[t][1][r] * vv;
    }
  }
  up0 += __shfl_xor(up0, 16); up0 += __shfl_xor(up0, 32);
  up1 += __shfl_xor(up1, 16); up1 += __shfl_xor(up1, 32);
  if (l < 16) {
    const int n0 = 32 * w + l, n1 = n0 + 16;
    wlog[n0] = up0 * rsqrtf(fmaxf(r2s[n0], 1e-12f)) + bias[n0];
    wlog[n1] = up1 * rsqrtf(fmaxf(r2s[n1], 1e-12f)) + bias[n1];
  }
  __syncthreads();

  // softmax over the 256 logits (wave 0)
  if (tid < 64) {
    const float a0 = wlog[tid], a1 = wlog[tid + 64], a2 = wlog[tid + 128], a3 = wlog[tid + 192];
    float mx = fmaxf(fmaxf(a0, a1), fmaxf(a2, a3));
    #pragma unroll
    for (int off = 32; off >= 1; off >>= 1) mx = fmaxf(mx, __shfl_xor(mx, off));
    const float e0 = __expf(a0 - mx), e1 = __expf(a1 - mx), e2 = __expf(a2 - mx), e3 = __expf(a3 - mx);
    float s = e0 + e1 + e2 + e3;
    #pragma unroll
    for (int off = 32; off >= 1; off >>= 1) s += __shfl_xor(s, off);
    const float inv = 1.0f / s;
    wexp[tid] = e0 * inv; wexp[tid + 64] = e1 * inv;
    wexp[tid + 128] = e2 * inv; wexp[tid + 192] = e3 * inv;
  }
  __syncthreads();

  // ---- output: out = p[row] * x (x from LDS bf16), plain f32 stores ----
  float* __restrict__ ob = out + (size_t)b * NELEM;
  #pragma unroll 4
  for (int i = 0; i < 16; ++i) {
    const int e8 = i * 4096 + tid * 8;
    const int r = e8 >> 8;
    const int q = (e8 >> 3) & 31;
    union { short8 v; unsigned short us[8]; } P;
    P.v = *reinterpret_cast<const short8*>(&Xs[(r << 8) + ((q ^ (r & 7)) << 3)]);
    const float wt = wexp[r];
    f32x4 o0, o1;
    o0[0] = bf2f(P.us[0]) * wt; o0[1] = bf2f(P.us[1]) * wt;
    o0[2] = bf2f(P.us[2]) * wt; o0[3] = bf2f(P.us[3]) * wt;
    o1[0] = bf2f(P.us[4]) * wt; o1[1] = bf2f(P.us[5]) * wt;
    o1[2] = bf2f(P.us[6]) * wt; o1[3] = bf2f(P.us[7]) * wt;
    *reinterpret_cast<f32x4*>(ob + e8)     = o0;
    *reinterpret_cast<f32x4*>(ob + e8 + 4) = o1;
  }
}

extern "C" void kernel_launch(void* const* d_in, const int* in_sizes, int n_in,
                              void* d_out, int out_size, void* d_ws, size_t ws_size,
                              hipStream_t stream) {
  const float* x    = (const float*)d_in[0];
  const float* kern = (const float*)d_in[1];
  const float* bias = (const float*)d_in[2];
  float* out = (float*)d_out;
  const int nb = in_sizes[0] / NELEM;          // 512 batches
  spat_attn<<<dim3(nb), dim3(512), 0, stream>>>(x, kern, bias, out);
}